// Round 1
// 1408.100 us; speedup vs baseline: 1.0409x; 1.0409x over previous
//
#include <hip/hip_runtime.h>
#include <math.h>

#define BB 64
#define KVLEN 2048
#define HID 4096
#define NH 32
#define NKVH 8
#define DH 128
#define GQ 4
#define QKV_N ((NH + 2 * NKVH) * DH) /* 6144 */
#define KSPLIT 16

// ---------------- transpose: src[64][K] -> dst[K][64] ----------------
__global__ __launch_bounds__(256) void transpose64(const float* __restrict__ src,
                                                   float* __restrict__ dst, int K) {
  __shared__ float t[64][65];
  int lane = threadIdx.x & 63;
  int w = threadIdx.x >> 6;
  int c0 = blockIdx.x * 64;
#pragma unroll
  for (int i = 0; i < 16; ++i) {
    int r = w * 16 + i;
    t[r][lane] = src[(size_t)r * K + c0 + lane];
  }
  __syncthreads();
#pragma unroll
  for (int i = 0; i < 16; ++i) {
    int c = w * 16 + i;
    dst[(size_t)(c0 + c) * 64 + lane] = t[lane][c];
  }
}

// ---------------- skinny GEMM: part[kc][64][N] = At[kchunk][64]^T @ W[kchunk][N] ----------------
// lane = column (coalesced W stream), wave owns 16 rows via wave-uniform A loads (s_load).
__global__ __launch_bounds__(256) void gemm_skinny_t(const float* __restrict__ At,
                                                     const float* __restrict__ W,
                                                     float* __restrict__ part,
                                                     int N, int kchunk) {
  int lane = threadIdx.x & 63;
  int wave = __builtin_amdgcn_readfirstlane((int)(threadIdx.x >> 6));
  int r0 = wave * 16;
  int n = blockIdx.x * 64 + lane;
  int k0 = blockIdx.y * kchunk;
  const float* Ap = At + (size_t)k0 * 64 + r0;
  const float* Wp = W + (size_t)k0 * N + n;
  float acc[16];
#pragma unroll
  for (int j = 0; j < 16; ++j) acc[j] = 0.f;
#pragma unroll 4
  for (int k = 0; k < kchunk; ++k) {
    float wv = Wp[(size_t)k * N];
    const float* a = Ap + (size_t)k * 64;
#pragma unroll
    for (int j = 0; j < 16; ++j) acc[j] = fmaf(a[j], wv, acc[j]);
  }
  float* op = part + ((size_t)blockIdx.y * 64 + r0) * N + n;
#pragma unroll
  for (int j = 0; j < 16; ++j) op[(size_t)j * N] = acc[j];
}

// ---------------- sum k-split partials + bias ----------------
__global__ __launch_bounds__(256) void reduce_add(const float4* __restrict__ part,
                                                  const float4* __restrict__ bias,
                                                  float4* __restrict__ out,
                                                  int n4, int total4, int nch) {
  int i = blockIdx.x * 256 + threadIdx.x;
  if (i >= total4) return;
  float4 a = bias[i % n4];
  for (int c = 0; c < nch; ++c) {
    float4 p = part[(size_t)c * total4 + i];
    a.x += p.x; a.y += p.y; a.z += p.z; a.w += p.w;
  }
  out[i] = a;
}

// ---------------- RoPE (neox, rotate halves) in-place on q (+scale) and k_new ----------------
__global__ __launch_bounds__(256) void rope_kernel(float* __restrict__ qkv,
                                                   const int* __restrict__ positions) {
  int idx = blockIdx.x * 256 + threadIdx.x; // B * 40 heads * 64 pairs
  int d = idx & 63;
  int hb = idx >> 6;
  int head = hb % (NH + NKVH);
  int b = hb / (NH + NKVH);
  float* base = qkv + (size_t)b * QKV_N + (size_t)head * DH;
  double inv_freq = exp2(-(double)d * (13.287712379549449 / 64.0));
  double ang = (double)positions[b] * inv_freq;
  double sd, cd;
  sincos(ang, &sd, &cd);
  float c = (float)cd, s = (float)sd;
  float x1 = base[d], x2 = base[d + 64];
  float scale = (head < NH) ? 0.08838834764831845f : 1.0f; // fold SCALE into q
  base[d] = (x1 * c - x2 * s) * scale;
  base[d + 64] = (x2 * c + x1 * s) * scale;
}

// ---------------- GQA decode attention: one 512-thread block per (b, kvh) ----------------
// Writes output TRANSPOSED: attnT[col][b] so the out-proj GEMM gets A^T for free.
#define DOT4(accrow, kv)                                                                  \
  accrow[0] = fmaf(kv.x, q0.x, fmaf(kv.y, q0.y, fmaf(kv.z, q0.z, fmaf(kv.w, q0.w, accrow[0])))); \
  accrow[1] = fmaf(kv.x, q1.x, fmaf(kv.y, q1.y, fmaf(kv.z, q1.z, fmaf(kv.w, q1.w, accrow[1])))); \
  accrow[2] = fmaf(kv.x, q2.x, fmaf(kv.y, q2.y, fmaf(kv.z, q2.z, fmaf(kv.w, q2.w, accrow[2])))); \
  accrow[3] = fmaf(kv.x, q3.x, fmaf(kv.y, q3.y, fmaf(kv.z, q3.z, fmaf(kv.w, q3.w, accrow[3]))));

__global__ __launch_bounds__(512, 4) void attn_kernel(const float* __restrict__ kcache,
                                                      const float* __restrict__ vcache,
                                                      const float* __restrict__ qkv,
                                                      float* __restrict__ attnT) {
  int b = blockIdx.x >> 3;
  int kvh = blockIdx.x & 7;
  int tid = threadIdx.x;
  int lane = tid & 63;
  int wave = tid >> 6;

  __shared__ float q_s[4][DH];            // 2 KB
  __shared__ float p_s[KVLEN * 4 + 4];    // 32.8 KB  [s][h]
  __shared__ float red[8][4];             // [wave][h]
  __shared__ float4 comb[3][128];         // 6 KB

  // load the 4 q heads of this kv group (already scaled by SCALE in rope)
  const float* qb = qkv + (size_t)b * QKV_N + (size_t)(kvh * GQ) * DH;
  q_s[tid >> 7][tid & 127] = qb[tid]; // 512 threads cover 4*128
  __syncthreads();

  // ---- pass 1: QK^T, 4 rows per thread, kept in registers ----
  const float* Kb = kcache + ((size_t)b * KVLEN * NKVH + kvh) * DH;
  float sc[4][4];
#pragma unroll
  for (int i = 0; i < 4; ++i)
#pragma unroll
    for (int hh = 0; hh < 4; ++hh) sc[i][hh] = 0.f;
  const float4* kr0 = (const float4*)(Kb + (size_t)(tid) * (NKVH * DH));
  const float4* kr1 = (const float4*)(Kb + (size_t)(tid + 512) * (NKVH * DH));
  const float4* kr2 = (const float4*)(Kb + (size_t)(tid + 1024) * (NKVH * DH));
  const float4* kr3 = (const float4*)(Kb + (size_t)(tid + 1536) * (NKVH * DH));
#pragma unroll 4
  for (int d4 = 0; d4 < 32; ++d4) {
    float4 q0 = *(const float4*)&q_s[0][d4 * 4];
    float4 q1 = *(const float4*)&q_s[1][d4 * 4];
    float4 q2 = *(const float4*)&q_s[2][d4 * 4];
    float4 q3 = *(const float4*)&q_s[3][d4 * 4];
    float4 t0 = kr0[d4];
    float4 t1 = kr1[d4];
    float4 t2 = kr2[d4];
    float4 t3 = kr3[d4];
    DOT4(sc[0], t0)
    DOT4(sc[1], t1)
    DOT4(sc[2], t2)
    DOT4(sc[3], t3)
  }

  // ---- new-token (s = KV) scores by wave 0 ----
  if (wave == 0) {
    const float* kn = qkv + (size_t)b * QKV_N + NH * DH + (size_t)kvh * DH;
    float k1v = kn[lane], k2v = kn[lane + 64];
    float pn[4];
#pragma unroll
    for (int h = 0; h < 4; ++h)
      pn[h] = k1v * q_s[h][lane] + k2v * q_s[h][lane + 64];
#pragma unroll
    for (int off = 32; off > 0; off >>= 1) {
#pragma unroll
      for (int h = 0; h < 4; ++h) pn[h] += __shfl_down(pn[h], off);
    }
    if (lane == 0) {
#pragma unroll
      for (int h = 0; h < 4; ++h) p_s[KVLEN * 4 + h] = pn[h];
    }
  }
  __syncthreads();

  // ---- block max ----
  float mxl[4];
#pragma unroll
  for (int h = 0; h < 4; ++h) mxl[h] = p_s[KVLEN * 4 + h];
#pragma unroll
  for (int i = 0; i < 4; ++i)
#pragma unroll
    for (int h = 0; h < 4; ++h) mxl[h] = fmaxf(mxl[h], sc[i][h]);
#pragma unroll
  for (int off = 32; off > 0; off >>= 1) {
#pragma unroll
    for (int h = 0; h < 4; ++h) mxl[h] = fmaxf(mxl[h], __shfl_xor(mxl[h], off));
  }
  if (lane == 0) {
#pragma unroll
    for (int h = 0; h < 4; ++h) red[wave][h] = mxl[h];
  }
  __syncthreads();
  float mx[4];
#pragma unroll
  for (int h = 0; h < 4; ++h) {
    float m = red[0][h];
#pragma unroll
    for (int w = 1; w < 8; ++w) m = fmaxf(m, red[w][h]);
    mx[h] = m;
  }
  __syncthreads(); // before red reuse

  // ---- exp + block sum; write P to LDS ----
  float ls[4] = {0.f, 0.f, 0.f, 0.f};
#pragma unroll
  for (int i = 0; i < 4; ++i) {
    int s = i * 512 + tid;
#pragma unroll
    for (int h = 0; h < 4; ++h) {
      float e = __expf(sc[i][h] - mx[h]);
      p_s[s * 4 + h] = e;
      ls[h] += e;
    }
  }
  if (tid < 4) {
    float e = __expf(p_s[KVLEN * 4 + tid] - mx[tid]);
    p_s[KVLEN * 4 + tid] = e;
    ls[tid] += e;
  }
#pragma unroll
  for (int off = 32; off > 0; off >>= 1) {
#pragma unroll
    for (int h = 0; h < 4; ++h) ls[h] += __shfl_xor(ls[h], off);
  }
  if (lane == 0) {
#pragma unroll
    for (int h = 0; h < 4; ++h) red[wave][h] = ls[h];
  }
  __syncthreads();
  float inv[4];
#pragma unroll
  for (int h = 0; h < 4; ++h) {
    float t = 0.f;
#pragma unroll
    for (int w = 0; w < 8; ++w) t += red[w][h];
    inv[h] = 1.0f / t;
  }

  // ---- pass 3: O = P @ V. threads = (quarter, h, d4), 4-way s-split ----
  int quarter = tid >> 7;
  int r = tid & 127;
  int h = r >> 5;
  int d4 = r & 31;
  const float4* Vb = (const float4*)(vcache + ((size_t)b * KVLEN * NKVH + kvh) * DH);
  float4 acc = {0.f, 0.f, 0.f, 0.f};
  int s0 = quarter * 512;
  int s1 = s0 + 512;
#pragma unroll 8
  for (int s = s0; s < s1; ++s) {
    float4 v4 = Vb[(size_t)s * (NKVH * DH / 4) + d4];
    float p = p_s[s * 4 + h];
    acc.x = fmaf(p, v4.x, acc.x);
    acc.y = fmaf(p, v4.y, acc.y);
    acc.z = fmaf(p, v4.z, acc.z);
    acc.w = fmaf(p, v4.w, acc.w);
  }
  if (quarter == 3) { // s = KV: v_new from qkv buffer
    const float* vn = qkv + (size_t)b * QKV_N + (NH + NKVH) * DH + (size_t)kvh * DH;
    float4 v4 = *(const float4*)(vn + d4 * 4);
    float p = p_s[KVLEN * 4 + h];
    acc.x = fmaf(p, v4.x, acc.x);
    acc.y = fmaf(p, v4.y, acc.y);
    acc.z = fmaf(p, v4.z, acc.z);
    acc.w = fmaf(p, v4.w, acc.w);
  }
  if (quarter > 0) comb[quarter - 1][r] = acc;
  __syncthreads();
  if (quarter == 0) {
    float4 c0 = comb[0][r], c1 = comb[1][r], c2 = comb[2][r];
    float iv = inv[h];
    float ox = (acc.x + c0.x + c1.x + c2.x) * iv;
    float oy = (acc.y + c0.y + c1.y + c2.y) * iv;
    float oz = (acc.z + c0.z + c1.z + c2.z) * iv;
    float ow = (acc.w + c0.w + c1.w + c2.w) * iv;
    // transposed store: attnT[col][b], col = kvh*512 + r*4 + j
    float* op = attnT + ((size_t)(kvh * 512 + r * 4)) * 64 + b;
    op[0] = ox;
    op[64] = oy;
    op[128] = oz;
    op[192] = ow;
  }
}

extern "C" void kernel_launch(void* const* d_in, const int* in_sizes, int n_in,
                              void* d_out, int out_size, void* d_ws, size_t ws_size,
                              hipStream_t stream) {
  (void)in_sizes; (void)n_in; (void)out_size; (void)ws_size;
  const float* h    = (const float*)d_in[0];
  const float* kc   = (const float*)d_in[1];
  const float* vc   = (const float*)d_in[2];
  const int*   pos  = (const int*)d_in[3];
  const float* Wqkv = (const float*)d_in[4];
  const float* bqkv = (const float*)d_in[5];
  const float* Wo   = (const float*)d_in[6];
  const float* bo   = (const float*)d_in[7];
  float* out = (float*)d_out;

  float* ht    = (float*)d_ws;                        // [4096][64]   1 MB
  float* qkv   = ht + (size_t)HID * BB;               // [64][6144]   1.5 MB
  float* part1 = qkv + (size_t)BB * QKV_N;            // [16][64][6144] 25 MB
  float* attnT = part1 + (size_t)KSPLIT * BB * QKV_N; // [4096][64]   1 MB
  float* part2 = attnT + (size_t)HID * BB;            // [16][64][4096] 17 MB

  // 1. h^T
  transpose64<<<HID / 64, 256, 0, stream>>>(h, ht, HID);

  // 2. qkv partials = h @ Wqkv  (N=6144, K=4096, k-split 16)
  dim3 g1(QKV_N / 64, KSPLIT);
  gemm_skinny_t<<<g1, 256, 0, stream>>>(ht, Wqkv, part1, QKV_N, HID / KSPLIT);

  // 3. qkv = sum(partials) + bqkv
  reduce_add<<<(BB * QKV_N / 4) / 256, 256, 0, stream>>>(
      (const float4*)part1, (const float4*)bqkv, (float4*)qkv,
      QKV_N / 4, BB * QKV_N / 4, KSPLIT);

  // 4. RoPE on q (+SCALE) and k_new, in place
  rope_kernel<<<(BB * (NH + NKVH) * 64) / 256, 256, 0, stream>>>(qkv, pos);

  // 5. attention -> attnT[4096][64] (transposed)
  attn_kernel<<<BB * NKVH, 512, 0, stream>>>(kc, vc, qkv, attnT);

  // 6. out partials = attn @ Wo  (N=4096, K=4096, k-split 16)
  dim3 g2(HID / 64, KSPLIT);
  gemm_skinny_t<<<g2, 256, 0, stream>>>(attnT, Wo, part2, HID, HID / KSPLIT);

  // 7. out = sum(partials) + bo
  reduce_add<<<(BB * HID / 4) / 256, 256, 0, stream>>>(
      (const float4*)part2, (const float4*)bo, (float4*)out,
      HID / 4, BB * HID / 4, KSPLIT);
}